// Round 10
// baseline (429.212 us; speedup 1.0000x reference)
//
#include <hip/hip_runtime.h>
#include <hip/hip_fp16.h>
#include <hip/hip_cooperative_groups.h>

namespace cg = cooperative_groups;

// Problem constants (fixed instance)
#define T_TOK 2048
#define K_DIM 2048
#define I_DIM 1024
#define NE    8
#define TOPK  2
#define GS    64

#define NSLOT  (T_TOK * TOPK)      // 4096 routed slots
#define TOTROW (NSLOT + T_TOK)     // + shared-expert rows = 6144
#define MAXITEM 32                 // max (expert, 256-row m-tile) work items

typedef __attribute__((ext_vector_type(8))) _Float16 half8; // 8 f16 (MFMA A/B frag)
typedef __attribute__((ext_vector_type(4))) float f32x4;    // MFMA C/D frag

// ---- workspace layout (bytes) ----
// 0: gcnt[16] | 64: gbase[16] | 128: tileCnt | 192: tileE[64] | 448: tileM[64]
// 1024: tok[6144] | 25600: inv[4096]
#define WS_XB   ((size_t)65536)                        // ushort xb[2048][2048] (f16)
#define WS_ACT  (WS_XB  + (size_t)2048 * 2048 * 2)     // ushort act[TOTROW][1024]
#define WS_Y    (WS_ACT + (size_t)TOTROW * 1024 * 2)   // ushort y[TOTROW][2048]
// total ~46 MB (fp4->f16 dequant fused into the GEMMs; no materialized weights)

// k-permutation sigma = {0,2,4,6,1,3,5,7} within each 8-block on BOTH operands
// (dot-product invariant); falls out of the byte-parallel nibble decode.
// NUMERICS: fp16 pipeline; fp4 codebook exact in fp16 with zero low byte.

__device__ __forceinline__ float h2f(ushort h) {
    __half v = *reinterpret_cast<__half*>(&h);
    return __half2float(v);
}

// one packed word (8 fp4 along k) -> 8 f16 (sigma k-order) scaled by S=half2(s,s)
__device__ __forceinline__ void dq_word(unsigned w, __half2 S, unsigned o[4]) {
    unsigned lo  = w & 0x0F0F0F0Fu;
    unsigned hi  = (w >> 4) & 0x0F0F0F0Fu;
    unsigned mlo = lo & 0x07070707u, mhi = hi & 0x07070707u;
    // hi-byte table of f16{0,.5,1,1.5,2,3,4,6}; lo bytes are all 0x00
    unsigned Hlo = __builtin_amdgcn_perm(0x46444240u, 0x3E3C3800u, mlo)
                 | ((lo & 0x08080808u) << 4);          // sign -> f16 bit15
    unsigned Hhi = __builtin_amdgcn_perm(0x46444240u, 0x3E3C3800u, mhi)
                 | ((hi & 0x08080808u) << 4);
    unsigned e01 = __builtin_amdgcn_perm(Hlo, 0u, 0x05000400u); // {k2:k0}
    unsigned e23 = __builtin_amdgcn_perm(Hlo, 0u, 0x07000600u); // {k6:k4}
    unsigned o01 = __builtin_amdgcn_perm(Hhi, 0u, 0x05000400u); // {k3:k1}
    unsigned o23 = __builtin_amdgcn_perm(Hhi, 0u, 0x07000600u); // {k7:k5}
    __half2 v0 = __hmul2(*reinterpret_cast<__half2*>(&e01), S);
    __half2 v1 = __hmul2(*reinterpret_cast<__half2*>(&e23), S);
    __half2 v2 = __hmul2(*reinterpret_cast<__half2*>(&o01), S);
    __half2 v3 = __hmul2(*reinterpret_cast<__half2*>(&o23), S);
    o[0] = *reinterpret_cast<unsigned*>(&v0);
    o[1] = *reinterpret_cast<unsigned*>(&v1);
    o[2] = *reinterpret_cast<unsigned*>(&v2);
    o[3] = *reinterpret_cast<unsigned*>(&v3);
}

__device__ __forceinline__ void gld16(const void* g, void* l) {
    __builtin_amdgcn_global_load_lds(
        (const __attribute__((address_space(1))) unsigned*)g,
        (__attribute__((address_space(3))) unsigned*)l, 16, 0, 0);
}

// ================= fused cooperative kernel =================
// 512 blocks x 512 threads, 48 KB LDS, <=128 regs/wave -> exactly 2 blocks/CU
// co-resident on 256 CUs (cooperative-launch requirement). Four stages
// separated by grid.sync(); stage bodies are the r7-champion kernels verbatim.
// This removes 3 kernel-launch boundaries (~25 us each per the cross-round
// ledger: measured dispatch sum ~138 us vs 229 us total).
#define FGRID 512

__global__ __launch_bounds__(512, 4) void k_fused(
        const float* __restrict__ x,
        const int* __restrict__ gup, const float* __restrict__ gus,
        const int* __restrict__ dwp, const float* __restrict__ dsc,
        const int* __restrict__ sup, const float* __restrict__ sus,
        const int* __restrict__ sdp, const float* __restrict__ sds,
        const int* __restrict__ eids, const float* __restrict__ prb,
        float* __restrict__ out,
        ushort* __restrict__ xb, ushort* __restrict__ act, ushort* __restrict__ y,
        int* __restrict__ gcnt, int* __restrict__ gbase,
        int* __restrict__ tileCnt, int* __restrict__ tileE, int* __restrict__ tileM,
        int* __restrict__ tok, int* __restrict__ inv) {
    cg::grid_group grid = cg::this_grid();
    const int bid = blockIdx.x;
    const int tid = threadIdx.x;

    __shared__ __align__(16) ushort xs[256 * 64];      // 32 KB
    __shared__ __align__(16) ushort bs[128 * 64];      // 16 KB (48 KB total)

    // ---- stage 0: x fp32 -> sigma-f16 (all blocks); routing (block 0)
    for (int idx = bid * 512 + tid; idx < T_TOK * K_DIM / 8; idx += FGRID * 512) {
        const float4* p = (const float4*)(x + (size_t)idx * 8);
        float4 f0 = p[0], f1 = p[1];
        __half2 h0 = __floats2half2_rn(f0.x, f0.z);   // {k0,k2}
        __half2 h1 = __floats2half2_rn(f1.x, f1.z);   // {k4,k6}
        __half2 h2 = __floats2half2_rn(f0.y, f0.w);   // {k1,k3}
        __half2 h3 = __floats2half2_rn(f1.y, f1.w);   // {k5,k7}
        *(int4*)(xb + (size_t)idx * 8) = make_int4(
            *reinterpret_cast<unsigned*>(&h0), *reinterpret_cast<unsigned*>(&h1),
            *reinterpret_cast<unsigned*>(&h2), *reinterpret_cast<unsigned*>(&h3));
    }
    if (bid == 0) {
        int* lcnt  = (int*)xs;                         // alias LDS for routing
        int* lbase = lcnt + 8;
        int* lcur  = lbase + 8;
        if (tid < NE) lcnt[tid] = 0;
        __syncthreads();
        for (int i = tid; i < NSLOT; i += 512)
            atomicAdd(&lcnt[eids[i]], 1);
        __syncthreads();
        if (tid == 0) {
            int acc = 0;
            for (int e = 0; e < NE; e++) { lbase[e] = acc; acc += lcnt[e]; }
        }
        __syncthreads();
        if (tid < NE) lcur[tid] = lbase[tid];
        __syncthreads();
        for (int i = tid; i < NSLOT; i += 512) {
            int e = eids[i];
            int pos = atomicAdd(&lcur[e], 1);
            tok[pos] = i >> 1;
            inv[i] = pos;
        }
        for (int t = tid; t < T_TOK; t += 512)
            tok[NSLOT + t] = t;
        if (tid < NE) { gcnt[tid] = lcnt[tid]; gbase[tid] = lbase[tid]; }
        if (tid == 0) {
            gcnt[NE] = T_TOK; gbase[NE] = NSLOT;
            int nt = 0;
            for (int e = 0; e < NE + 1; e++) {
                int c = (e < NE) ? lcnt[e] : T_TOK;
                for (int m = 0; m < c; m += 256) { tileE[nt] = e; tileM[nt] = m; nt++; }
            }
            *tileCnt = nt;                             // <= 32 (routed<=23 + 8 shared)
            for (int i = nt; i < 64; i++) { tileE[i] = 0; tileM[i] = 0; }
        }
    }
    grid.sync();

    // ---- stage 1: gateup (r7 body; bid -> (x-block = bid&15, item = bid>>4))
    {
        int item = bid >> 4;
        if (item < *tileCnt) {
            int e = tileE[item], m0 = tileM[item];
            int cnt = gcnt[e], base = gbase[e];
            int n0 = (bid & 15) * 64;                  // gate-col base (64 wide)
            const int* wp; const float* sc;
            if (e < NE) { wp = gup + (size_t)e * 256 * 2048; sc = gus + (size_t)e * 32 * 2048; }
            else        { wp = sup; sc = sus; }

            int lane = tid & 63, wv = tid >> 6;        // 8 waves
            int lid = lane & 15, quad = lane >> 4;
            int wr = wv >> 1, wc = wv & 1;             // 4x2 waves of 64x64
            int l8 = lane >> 3, l7 = lane & 7;
            int chunk = (l7 ^ l8) * 8;

            const ushort* aSrc[4];
            #pragma unroll
            for (int it = 0; it < 4; it++) {
                int rA = wv * 32 + it * 8 + l8;        // rA & 7 == l8
                int t = (m0 + rA < cnt) ? tok[base + m0 + rA] : 0;
                aSrc[it] = xb + (size_t)t * K_DIM + chunk;
            }

            int nloc = tid & 127;
            int kw0 = (tid >> 7) * 2;                  // {0,2,4,6}
            int bj = nloc & 63, bh = nloc >> 6;
            int ncol = (bj < 32) ? (n0 + bh * 32 + bj) : (I_DIM + n0 + bh * 32 + (bj - 32));
            int bd0 = nloc * 64 + ((kw0    ) ^ (nloc & 7)) * 8;
            int bd1 = nloc * 64 + ((kw0 + 1) ^ (nloc & 7)) * 8;

            const int NT = K_DIM / 64;                 // 32 k-tiles
            const int* wq = wp + (size_t)kw0 * 2048 + ncol;
            const float* sq = sc + ncol;
            unsigned w0 = (unsigned)wq[0];
            unsigned w1 = (unsigned)wq[2048];
            float s = *sq;
            wq += 16384; sq += 2048;

            f32x4 acc[4][4] = {};

            for (int t = 0; t < NT; ++t) {
                #pragma unroll
                for (int it = 0; it < 4; it++) {
                    gld16(aSrc[it], &xs[(wv * 4 + it) * 512]);
                    aSrc[it] += 64;
                }
                {
                    __half2 S = __half2half2(__float2half(s));
                    unsigned o[4];
                    dq_word(w0, S, o); *(int4*)&bs[bd0] = make_int4(o[0], o[1], o[2], o[3]);
                    dq_word(w1, S, o); *(int4*)&bs[bd1] = make_int4(o[0], o[1], o[2], o[3]);
                }
                if (t + 1 < NT) {                      // prefetch next k-step B
                    w0 = (unsigned)wq[0];
                    w1 = (unsigned)wq[2048];
                    s = *sq;
                    wq += 16384; sq += 2048;
                }
                __syncthreads();
                __builtin_amdgcn_s_setprio(1);
                #pragma unroll
                for (int ks = 0; ks < 2; ks++) {
                    int slot = ((ks * 4 + quad) ^ l7) * 8;
                    half8 a[4], b[4];
                    #pragma unroll
                    for (int mt = 0; mt < 4; mt++)
                        a[mt] = *(const half8*)&xs[(wr * 64 + mt * 16 + lid) * 64 + slot];
                    #pragma unroll
                    for (int nt = 0; nt < 4; nt++)
                        b[nt] = *(const half8*)&bs[(wc * 64 + nt * 16 + lid) * 64 + slot];
                    #pragma unroll
                    for (int mt = 0; mt < 4; mt++)
                        #pragma unroll
                        for (int nt = 0; nt < 4; nt++)
                            acc[mt][nt] = __builtin_amdgcn_mfma_f32_16x16x32_f16(
                                a[mt], b[nt], acc[mt][nt], 0, 0, 0);
                }
                __builtin_amdgcn_s_setprio(0);
                __syncthreads();
            }

            int c7 = lid & 7;
            int delta = ((c7 >> 1) + ((c7 & 1) << 2)) - c7;  // sigma^-1 on stored I idx
            #pragma unroll
            for (int mt = 0; mt < 4; mt++) {
                #pragma unroll
                for (int i = 0; i < 4; i++) {
                    int row = wr * 64 + mt * 16 + quad * 4 + i;
                    if (m0 + row < cnt) {
                        size_t p = (size_t)(base + m0 + row);
                        #pragma unroll
                        for (int nt = 0; nt < 2; nt++) {
                            float g = acc[mt][nt][i], u = acc[mt][nt + 2][i];
                            float vv = g / (1.f + __expf(-g)) * u;
                            int ncol2 = n0 + wc * 32 + nt * 16 + lid;
                            __half hb = __float2half(vv);
                            act[p * I_DIM + ncol2 + delta] = *reinterpret_cast<ushort*>(&hb);
                        }
                    }
                }
            }
        }
    }
    grid.sync();

    // ---- stage 2: down (r7 body; n0 = (bid&15)*128)
    {
        int item = bid >> 4;
        if (item < *tileCnt) {
            int e = tileE[item], m0 = tileM[item];
            int cnt = gcnt[e], base = gbase[e];
            int n0 = (bid & 15) * 128;
            const int* wp; const float* sc;
            if (e < NE) { wp = dwp + (size_t)e * 128 * 2048; sc = dsc + (size_t)e * 16 * 2048; }
            else        { wp = sdp; sc = sds; }

            int lane = tid & 63, wv = tid >> 6;
            int lid = lane & 15, quad = lane >> 4;
            int wr = wv >> 1, wc = wv & 1;
            int l8 = lane >> 3, l7 = lane & 7;
            int chunk = (l7 ^ l8) * 8;

            const ushort* aSrc[4];
            #pragma unroll
            for (int it = 0; it < 4; it++) {
                int rA = wv * 32 + it * 8 + l8;
                int rr = m0 + rA; if (rr >= cnt) rr = cnt - 1;
                aSrc[it] = act + (size_t)(base + rr) * I_DIM + chunk;
            }

            int nloc = tid & 127;
            int kw0 = (tid >> 7) * 2;
            int ncol = n0 + nloc;
            int bd0 = nloc * 64 + ((kw0    ) ^ (nloc & 7)) * 8;
            int bd1 = nloc * 64 + ((kw0 + 1) ^ (nloc & 7)) * 8;

            const int NT = I_DIM / 64;                 // 16 i-tiles
            const int* wq = wp + (size_t)kw0 * 2048 + ncol;
            const float* sq = sc + ncol;
            unsigned w0 = (unsigned)wq[0];
            unsigned w1 = (unsigned)wq[2048];
            float s = *sq;
            wq += 16384; sq += 2048;

            f32x4 acc[4][4] = {};

            for (int t = 0; t < NT; ++t) {
                #pragma unroll
                for (int it = 0; it < 4; it++) {
                    gld16(aSrc[it], &xs[(wv * 4 + it) * 512]);
                    aSrc[it] += 64;
                }
                {
                    __half2 S = __half2half2(__float2half(s));
                    unsigned o[4];
                    dq_word(w0, S, o); *(int4*)&bs[bd0] = make_int4(o[0], o[1], o[2], o[3]);
                    dq_word(w1, S, o); *(int4*)&bs[bd1] = make_int4(o[0], o[1], o[2], o[3]);
                }
                if (t + 1 < NT) {
                    w0 = (unsigned)wq[0];
                    w1 = (unsigned)wq[2048];
                    s = *sq;
                    wq += 16384; sq += 2048;
                }
                __syncthreads();
                __builtin_amdgcn_s_setprio(1);
                #pragma unroll
                for (int ks = 0; ks < 2; ks++) {
                    int slot = ((ks * 4 + quad) ^ l7) * 8;
                    half8 a[4], b[4];
                    #pragma unroll
                    for (int mt = 0; mt < 4; mt++)
                        a[mt] = *(const half8*)&xs[(wr * 64 + mt * 16 + lid) * 64 + slot];
                    #pragma unroll
                    for (int nt = 0; nt < 4; nt++)
                        b[nt] = *(const half8*)&bs[(wc * 64 + nt * 16 + lid) * 64 + slot];
                    #pragma unroll
                    for (int mt = 0; mt < 4; mt++)
                        #pragma unroll
                        for (int nt = 0; nt < 4; nt++)
                            acc[mt][nt] = __builtin_amdgcn_mfma_f32_16x16x32_f16(
                                a[mt], b[nt], acc[mt][nt], 0, 0, 0);
                }
                __builtin_amdgcn_s_setprio(0);
                __syncthreads();
            }

            #pragma unroll
            for (int mt = 0; mt < 4; mt++) {
                #pragma unroll
                for (int i = 0; i < 4; i++) {
                    int row = wr * 64 + mt * 16 + quad * 4 + i;
                    if (m0 + row < cnt) {
                        ushort* yrow = y + (size_t)(base + m0 + row) * 2048 + n0 + wc * 64 + lid;
                        #pragma unroll
                        for (int nt = 0; nt < 4; nt++) {
                            __half hb = __float2half(acc[mt][nt][i]);
                            yrow[nt * 16] = *reinterpret_cast<ushort*>(&hb);
                        }
                    }
                }
            }
        }
    }
    grid.sync();

    // ---- stage 3: combine: out[t] = p0*y[inv[2t]] + p1*y[inv[2t+1]] + y[NSLOT+t]
    for (int idx = bid * 512 + tid; idx < T_TOK * K_DIM / 8; idx += FGRID * 512) {
        int t = idx >> 8;
        int c = (idx & 255) * 8;
        int p0 = inv[2 * t], p1 = inv[2 * t + 1];
        float w0 = prb[2 * t], w1 = prb[2 * t + 1];
        int4 a = *(const int4*)(y + (size_t)p0 * 2048 + c);
        int4 b = *(const int4*)(y + (size_t)p1 * 2048 + c);
        int4 sv = *(const int4*)(y + (size_t)(NSLOT + t) * 2048 + c);
        const ushort* au = (const ushort*)&a;
        const ushort* bu = (const ushort*)&b;
        const ushort* su = (const ushort*)&sv;
        float o[8];
        #pragma unroll
        for (int j = 0; j < 8; j++)
            o[j] = w0 * h2f(au[j]) + w1 * h2f(bu[j]) + h2f(su[j]);
        *(float4*)(out + (size_t)t * 2048 + c)     = *(float4*)&o[0];
        *(float4*)(out + (size_t)t * 2048 + c + 4) = *(float4*)&o[4];
    }
}

// ================= r7 four-kernel fallback (used only if cooperative launch fails)

#define PREP_BLK 2048
#define FRONT_GRID (PREP_BLK + 1)

__global__ __launch_bounds__(256) void k_front(
        const float* __restrict__ x, ushort* __restrict__ xb,
        const int* __restrict__ eids,
        int* __restrict__ gcnt, int* __restrict__ gbase,
        int* __restrict__ tileCnt, int* __restrict__ tileE, int* __restrict__ tileM,
        int* __restrict__ tok, int* __restrict__ inv) {
    int id = blockIdx.x;
    int tid = threadIdx.x;

    if (id < PREP_BLK) {
        int idx = id * 256 + tid;
        const float4* p = (const float4*)(x + (size_t)idx * 8);
        float4 f0 = p[0], f1 = p[1];
        __half2 h0 = __floats2half2_rn(f0.x, f0.z);
        __half2 h1 = __floats2half2_rn(f1.x, f1.z);
        __half2 h2 = __floats2half2_rn(f0.y, f0.w);
        __half2 h3 = __floats2half2_rn(f1.y, f1.w);
        *(int4*)(xb + (size_t)idx * 8) = make_int4(
            *reinterpret_cast<unsigned*>(&h0), *reinterpret_cast<unsigned*>(&h1),
            *reinterpret_cast<unsigned*>(&h2), *reinterpret_cast<unsigned*>(&h3));
    } else {
        __shared__ int lcnt[NE], lbase[NE], lcur[NE];
        if (tid < NE) lcnt[tid] = 0;
        __syncthreads();
        for (int i = tid; i < NSLOT; i += 256)
            atomicAdd(&lcnt[eids[i]], 1);
        __syncthreads();
        if (tid == 0) {
            int acc = 0;
            for (int e = 0; e < NE; e++) { lbase[e] = acc; acc += lcnt[e]; }
        }
        __syncthreads();
        if (tid < NE) lcur[tid] = lbase[tid];
        __syncthreads();
        for (int i = tid; i < NSLOT; i += 256) {
            int e = eids[i];
            int pos = atomicAdd(&lcur[e], 1);
            tok[pos] = i >> 1;
            inv[i] = pos;
        }
        for (int t = tid; t < T_TOK; t += 256)
            tok[NSLOT + t] = t;
        if (tid < NE) { gcnt[tid] = lcnt[tid]; gbase[tid] = lbase[tid]; }
        if (tid == 0) {
            gcnt[NE] = T_TOK; gbase[NE] = NSLOT;
            int nt = 0;
            for (int e = 0; e < NE + 1; e++) {
                int c = (e < NE) ? lcnt[e] : T_TOK;
                for (int m = 0; m < c; m += 256) { tileE[nt] = e; tileM[nt] = m; nt++; }
            }
            *tileCnt = nt;
            for (int i = nt; i < 64; i++) { tileE[i] = 0; tileM[i] = 0; }
        }
    }
}

__global__ __launch_bounds__(512) void k_gemm_gateup(
        const ushort* __restrict__ xb,
        const int* __restrict__ gup, const float* __restrict__ gus,
        const int* __restrict__ sup, const float* __restrict__ sus,
        const int* __restrict__ gcnt, const int* __restrict__ gbase,
        const int* __restrict__ tileCnt, const int* __restrict__ tileE,
        const int* __restrict__ tileM,
        const int* __restrict__ tokid, ushort* __restrict__ act) {
    int item = blockIdx.y;
    if (item >= *tileCnt) return;
    int tid = threadIdx.x;
    int e = tileE[item], m0 = tileM[item];
    int cnt = gcnt[e], base = gbase[e];
    int n0 = blockIdx.x * 64;
    const int* wp; const float* sc;
    if (e < NE) { wp = gup + (size_t)e * 256 * 2048; sc = gus + (size_t)e * 32 * 2048; }
    else        { wp = sup; sc = sus; }

    __shared__ __align__(16) ushort xs[256 * 64];
    __shared__ __align__(16) ushort bs[128 * 64];

    int lane = tid & 63, wv = tid >> 6;
    int lid = lane & 15, quad = lane >> 4;
    int wr = wv >> 1, wc = wv & 1;
    int l8 = lane >> 3, l7 = lane & 7;
    int chunk = (l7 ^ l8) * 8;

    const ushort* aSrc[4];
    #pragma unroll
    for (int it = 0; it < 4; it++) {
        int rA = wv * 32 + it * 8 + l8;
        int t = (m0 + rA < cnt) ? tokid[base + m0 + rA] : 0;
        aSrc[it] = xb + (size_t)t * K_DIM + chunk;
    }

    int nloc = tid & 127;
    int kw0 = (tid >> 7) * 2;
    int bj = nloc & 63, bh = nloc >> 6;
    int ncol = (bj < 32) ? (n0 + bh * 32 + bj) : (I_DIM + n0 + bh * 32 + (bj - 32));
    int bd0 = nloc * 64 + ((kw0    ) ^ (nloc & 7)) * 8;
    int bd1 = nloc * 64 + ((kw0 + 1) ^ (nloc & 7)) * 8;

    const int NT = K_DIM / 64;
    const int* wq = wp + (size_t)kw0 * 2048 + ncol;
    const float* sq = sc + ncol;
    unsigned w0 = (unsigned)wq[0];
    unsigned w1 = (unsigned)wq[2048];
    float s = *sq;
    wq += 16384; sq += 2048;

    f32x4 acc[4][4] = {};

    for (int t = 0; t < NT; ++t) {
        #pragma unroll
        for (int it = 0; it < 4; it++) {
            gld16(aSrc[it], &xs[(wv * 4 + it) * 512]);
            aSrc[it] += 64;
        }
        {
            __half2 S = __half2half2(__float2half(s));
            unsigned o[4];
            dq_word(w0, S, o); *(int4*)&bs[bd0] = make_int4(o[0], o[1], o[2], o[3]);
            dq_word(w1, S, o); *(int4*)&bs[bd1] = make_int4(o[0], o[1], o[2], o[3]);
        }
        if (t + 1 < NT) {
            w0 = (unsigned)wq[0];
            w1 = (unsigned)wq[2048];
            s = *sq;
            wq += 16384; sq += 2048;
        }
        __syncthreads();
        __builtin_amdgcn_s_setprio(1);
        #pragma unroll
        for (int ks = 0; ks < 2; ks++) {
            int slot = ((ks * 4 + quad) ^ l7) * 8;
            half8 a[4], b[4];
            #pragma unroll
            for (int mt = 0; mt < 4; mt++)
                a[mt] = *(const half8*)&xs[(wr * 64 + mt * 16 + lid) * 64 + slot];
            #pragma unroll
            for (int nt = 0; nt < 4; nt++)
                b[nt] = *(const half8*)&bs[(wc * 64 + nt * 16 + lid) * 64 + slot];
            #pragma unroll
            for (int mt = 0; mt < 4; mt++)
                #pragma unroll
                for (int nt = 0; nt < 4; nt++)
                    acc[mt][nt] = __builtin_amdgcn_mfma_f32_16x16x32_f16(
                        a[mt], b[nt], acc[mt][nt], 0, 0, 0);
        }
        __builtin_amdgcn_s_setprio(0);
        __syncthreads();
    }

    int c7 = lid & 7;
    int delta = ((c7 >> 1) + ((c7 & 1) << 2)) - c7;
    #pragma unroll
    for (int mt = 0; mt < 4; mt++) {
        #pragma unroll
        for (int i = 0; i < 4; i++) {
            int row = wr * 64 + mt * 16 + quad * 4 + i;
            if (m0 + row < cnt) {
                size_t p = (size_t)(base + m0 + row);
                #pragma unroll
                for (int nt = 0; nt < 2; nt++) {
                    float g = acc[mt][nt][i], u = acc[mt][nt + 2][i];
                    float vv = g / (1.f + __expf(-g)) * u;
                    int ncol2 = n0 + wc * 32 + nt * 16 + lid;
                    __half hb = __float2half(vv);
                    act[p * I_DIM + ncol2 + delta] = *reinterpret_cast<ushort*>(&hb);
                }
            }
        }
    }
}

__global__ __launch_bounds__(512) void k_gemm_down(
        const ushort* __restrict__ actb,
        const int* __restrict__ dwp, const float* __restrict__ dsc,
        const int* __restrict__ sdp, const float* __restrict__ sds,
        const int* __restrict__ gcnt, const int* __restrict__ gbase,
        const int* __restrict__ tileCnt, const int* __restrict__ tileE,
        const int* __restrict__ tileM,
        ushort* __restrict__ y) {
    int item = blockIdx.y;
    if (item >= *tileCnt) return;
    int tid = threadIdx.x;
    int e = tileE[item], m0 = tileM[item];
    int cnt = gcnt[e], base = gbase[e];
    int n0 = blockIdx.x * 128;
    const int* wp; const float* sc;
    if (e < NE) { wp = dwp + (size_t)e * 128 * 2048; sc = dsc + (size_t)e * 16 * 2048; }
    else        { wp = sdp; sc = sds; }

    __shared__ __align__(16) ushort xs[256 * 64];
    __shared__ __align__(16) ushort bs[128 * 64];

    int lane = tid & 63, wv = tid >> 6;
    int lid = lane & 15, quad = lane >> 4;
    int wr = wv >> 1, wc = wv & 1;
    int l8 = lane >> 3, l7 = lane & 7;
    int chunk = (l7 ^ l8) * 8;

    const ushort* aSrc[4];
    #pragma unroll
    for (int it = 0; it < 4; it++) {
        int rA = wv * 32 + it * 8 + l8;
        int rr = m0 + rA; if (rr >= cnt) rr = cnt - 1;
        aSrc[it] = actb + (size_t)(base + rr) * I_DIM + chunk;
    }

    int nloc = tid & 127;
    int kw0 = (tid >> 7) * 2;
    int ncol = n0 + nloc;
    int bd0 = nloc * 64 + ((kw0    ) ^ (nloc & 7)) * 8;
    int bd1 = nloc * 64 + ((kw0 + 1) ^ (nloc & 7)) * 8;

    const int NT = I_DIM / 64;
    const int* wq = wp + (size_t)kw0 * 2048 + ncol;
    const float* sq = sc + ncol;
    unsigned w0 = (unsigned)wq[0];
    unsigned w1 = (unsigned)wq[2048];
    float s = *sq;
    wq += 16384; sq += 2048;

    f32x4 acc[4][4] = {};

    for (int t = 0; t < NT; ++t) {
        #pragma unroll
        for (int it = 0; it < 4; it++) {
            gld16(aSrc[it], &xs[(wv * 4 + it) * 512]);
            aSrc[it] += 64;
        }
        {
            __half2 S = __half2half2(__float2half(s));
            unsigned o[4];
            dq_word(w0, S, o); *(int4*)&bs[bd0] = make_int4(o[0], o[1], o[2], o[3]);
            dq_word(w1, S, o); *(int4*)&bs[bd1] = make_int4(o[0], o[1], o[2], o[3]);
        }
        if (t + 1 < NT) {
            w0 = (unsigned)wq[0];
            w1 = (unsigned)wq[2048];
            s = *sq;
            wq += 16384; sq += 2048;
        }
        __syncthreads();
        __builtin_amdgcn_s_setprio(1);
        #pragma unroll
        for (int ks = 0; ks < 2; ks++) {
            int slot = ((ks * 4 + quad) ^ l7) * 8;
            half8 a[4], b[4];
            #pragma unroll
            for (int mt = 0; mt < 4; mt++)
                a[mt] = *(const half8*)&xs[(wr * 64 + mt * 16 + lid) * 64 + slot];
            #pragma unroll
            for (int nt = 0; nt < 4; nt++)
                b[nt] = *(const half8*)&bs[(wc * 64 + nt * 16 + lid) * 64 + slot];
            #pragma unroll
            for (int mt = 0; mt < 4; mt++)
                #pragma unroll
                for (int nt = 0; nt < 4; nt++)
                    acc[mt][nt] = __builtin_amdgcn_mfma_f32_16x16x32_f16(
                        a[mt], b[nt], acc[mt][nt], 0, 0, 0);
        }
        __builtin_amdgcn_s_setprio(0);
        __syncthreads();
    }

    #pragma unroll
    for (int mt = 0; mt < 4; mt++) {
        #pragma unroll
        for (int i = 0; i < 4; i++) {
            int row = wr * 64 + mt * 16 + quad * 4 + i;
            if (m0 + row < cnt) {
                ushort* yrow = y + (size_t)(base + m0 + row) * 2048 + n0 + wc * 64 + lid;
                #pragma unroll
                for (int nt = 0; nt < 4; nt++) {
                    __half hb = __float2half(acc[mt][nt][i]);
                    yrow[nt * 16] = *reinterpret_cast<ushort*>(&hb);
                }
            }
        }
    }
}

__global__ __launch_bounds__(256) void k_combine(
        const ushort* __restrict__ y, const int* __restrict__ inv,
        const float* __restrict__ prb, float* __restrict__ out) {
    int idx = blockIdx.x * 256 + threadIdx.x;
    int t = idx >> 8;
    int c = (idx & 255) * 8;
    int p0 = inv[2 * t], p1 = inv[2 * t + 1];
    float w0 = prb[2 * t], w1 = prb[2 * t + 1];
    int4 a = *(const int4*)(y + (size_t)p0 * 2048 + c);
    int4 b = *(const int4*)(y + (size_t)p1 * 2048 + c);
    int4 s = *(const int4*)(y + (size_t)(NSLOT + t) * 2048 + c);
    const ushort* au = (const ushort*)&a;
    const ushort* bu = (const ushort*)&b;
    const ushort* su = (const ushort*)&s;
    float o[8];
    #pragma unroll
    for (int j = 0; j < 8; j++)
        o[j] = w0 * h2f(au[j]) + w1 * h2f(bu[j]) + h2f(su[j]);
    *(float4*)(out + (size_t)t * 2048 + c)     = *(float4*)&o[0];
    *(float4*)(out + (size_t)t * 2048 + c + 4) = *(float4*)&o[4];
}

extern "C" void kernel_launch(void* const* d_in, const int* in_sizes, int n_in,
                              void* d_out, int out_size, void* d_ws, size_t ws_size,
                              hipStream_t stream) {
    const float* x    = (const float*)d_in[0];
    const int*   gup  = (const int*)d_in[1];
    const float* gus  = (const float*)d_in[2];
    const int*   dwp  = (const int*)d_in[3];
    const float* dsc  = (const float*)d_in[4];
    const int*   sup  = (const int*)d_in[5];
    const float* sus  = (const float*)d_in[6];
    const int*   sdp  = (const int*)d_in[7];
    const float* sds  = (const float*)d_in[8];
    const int*   eids = (const int*)d_in[9];
    const float* prb  = (const float*)d_in[10];
    float* out = (float*)d_out;

    char*   ws      = (char*)d_ws;
    int*    gcnt    = (int*)(ws + 0);
    int*    gbase   = (int*)(ws + 64);
    int*    tileCnt = (int*)(ws + 128);
    int*    tileE   = (int*)(ws + 192);
    int*    tileM   = (int*)(ws + 448);
    int*    tok     = (int*)(ws + 1024);
    int*    inv     = (int*)(ws + 25600);
    ushort* xb      = (ushort*)(ws + WS_XB);
    ushort* act     = (ushort*)(ws + WS_ACT);
    ushort* y       = (ushort*)(ws + WS_Y);

    void* args[] = {
        (void*)&x, (void*)&gup, (void*)&gus, (void*)&dwp, (void*)&dsc,
        (void*)&sup, (void*)&sus, (void*)&sdp, (void*)&sds,
        (void*)&eids, (void*)&prb, (void*)&out,
        (void*)&xb, (void*)&act, (void*)&y,
        (void*)&gcnt, (void*)&gbase, (void*)&tileCnt, (void*)&tileE, (void*)&tileM,
        (void*)&tok, (void*)&inv
    };
    hipError_t rc = hipLaunchCooperativeKernel(
        (const void*)k_fused, dim3(FGRID), dim3(512), args, 0, stream);
    if (rc != hipSuccess) {                            // fallback: r7 four-kernel path
        (void)hipGetLastError();
        k_front<<<FRONT_GRID, 256, 0, stream>>>(
            x, xb, eids, gcnt, gbase, tileCnt, tileE, tileM, tok, inv);
        k_gemm_gateup<<<dim3(I_DIM / 64, MAXITEM), 512, 0, stream>>>(
            xb, gup, gus, sup, sus, gcnt, gbase, tileCnt, tileE, tileM, tok, act);
        k_gemm_down<<<dim3(K_DIM / 128, MAXITEM), 512, 0, stream>>>(
            act, dwp, dsc, sdp, sds, gcnt, gbase, tileCnt, tileE, tileM, y);
        k_combine<<<(T_TOK * K_DIM / 8) / 256, 256, 0, stream>>>(y, inv, prb, out);
    }
}

// Round 11
// 228.805 us; speedup vs baseline: 1.8759x; 1.8759x over previous
//
#include <hip/hip_runtime.h>
#include <hip/hip_fp16.h>

// Problem constants (fixed instance)
#define T_TOK 2048
#define K_DIM 2048
#define I_DIM 1024
#define NE    8
#define TOPK  2
#define GS    64

#define NSLOT  (T_TOK * TOPK)      // 4096 routed slots
#define TOTROW (NSLOT + T_TOK)     // + shared-expert rows = 6144
#define MAXITEM 32                 // max (expert, 256-row m-tile) work items

typedef __attribute__((ext_vector_type(8))) _Float16 half8; // 8 f16 (MFMA A/B frag)
typedef __attribute__((ext_vector_type(4))) float f32x4;    // MFMA C/D frag

// ---- workspace layout (bytes) ----
#define WS_XB   ((size_t)65536)                        // ushort xb[2048][2048] (f16)
#define WS_ACT  (WS_XB  + (size_t)2048 * 2048 * 2)     // ushort act[TOTROW][1024]
#define WS_Y    (WS_ACT + (size_t)TOTROW * 1024 * 2)   // ushort y[TOTROW][2048]
// total ~46 MB (fp4->f16 dequant fused into the GEMMs; no materialized weights)

// k-permutation sigma = {0,2,4,6,1,3,5,7} within each 8-block on BOTH operands
// (dot-product invariant); falls out of the byte-parallel nibble decode.
// NUMERICS: fp16 pipeline; fp4 codebook exact in fp16 with zero low byte.
// CHAMPION STRUCTURE (verified over 10 structural experiments):
//  - 2-barrier loop {stage(A gld16 + B reg-dequant/ds_write); prefetch; sync;
//    setprio+MFMA; sync}, 8 waves, 64x64 wave-tiles, 48 KB LDS, 2 blocks/CU.
//  - All tested departures (dbuf, 8-phase, geometry, atomics, grid.sync
//    fusion) regressed; FETCH is compulsory-only, bank conflicts 0.

__device__ __forceinline__ float h2f(ushort h) {
    __half v = *reinterpret_cast<__half*>(&h);
    return __half2float(v);
}

// one packed word (8 fp4 along k) -> 8 f16 (sigma k-order) scaled by S=half2(s,s)
__device__ __forceinline__ void dq_word(unsigned w, __half2 S, unsigned o[4]) {
    unsigned lo  = w & 0x0F0F0F0Fu;
    unsigned hi  = (w >> 4) & 0x0F0F0F0Fu;
    unsigned mlo = lo & 0x07070707u, mhi = hi & 0x07070707u;
    // hi-byte table of f16{0,.5,1,1.5,2,3,4,6}; lo bytes are all 0x00
    unsigned Hlo = __builtin_amdgcn_perm(0x46444240u, 0x3E3C3800u, mlo)
                 | ((lo & 0x08080808u) << 4);          // sign -> f16 bit15
    unsigned Hhi = __builtin_amdgcn_perm(0x46444240u, 0x3E3C3800u, mhi)
                 | ((hi & 0x08080808u) << 4);
    unsigned e01 = __builtin_amdgcn_perm(Hlo, 0u, 0x05000400u); // {k2:k0}
    unsigned e23 = __builtin_amdgcn_perm(Hlo, 0u, 0x07000600u); // {k6:k4}
    unsigned o01 = __builtin_amdgcn_perm(Hhi, 0u, 0x05000400u); // {k3:k1}
    unsigned o23 = __builtin_amdgcn_perm(Hhi, 0u, 0x07000600u); // {k7:k5}
    __half2 v0 = __hmul2(*reinterpret_cast<__half2*>(&e01), S);
    __half2 v1 = __hmul2(*reinterpret_cast<__half2*>(&e23), S);
    __half2 v2 = __hmul2(*reinterpret_cast<__half2*>(&o01), S);
    __half2 v3 = __hmul2(*reinterpret_cast<__half2*>(&o23), S);
    o[0] = *reinterpret_cast<unsigned*>(&v0);
    o[1] = *reinterpret_cast<unsigned*>(&v1);
    o[2] = *reinterpret_cast<unsigned*>(&v2);
    o[3] = *reinterpret_cast<unsigned*>(&v3);
}

__device__ __forceinline__ void gld16(const void* g, void* l) {
    __builtin_amdgcn_global_load_lds(
        (const __attribute__((address_space(1))) unsigned*)g,
        (__attribute__((address_space(3))) unsigned*)l, 16, 0, 0);
}

// ---- front end: x prep + routing (weight dequant is fused into the GEMMs)
#define PREP_BLK 2048
#define FRONT_GRID (PREP_BLK + 1)

__global__ __launch_bounds__(256) void k_front(
        const float* __restrict__ x, ushort* __restrict__ xb,
        const int* __restrict__ eids,
        int* __restrict__ gcnt, int* __restrict__ gbase,
        int* __restrict__ tileCnt, int* __restrict__ tileE, int* __restrict__ tileM,
        int* __restrict__ tok, int* __restrict__ inv) {
    int id = blockIdx.x;
    int tid = threadIdx.x;

    if (id < PREP_BLK) {                              // x fp32 -> sigma-f16
        int idx = id * 256 + tid;
        const float4* p = (const float4*)(x + (size_t)idx * 8);
        float4 f0 = p[0], f1 = p[1];
        __half2 h0 = __floats2half2_rn(f0.x, f0.z);   // {k0,k2}
        __half2 h1 = __floats2half2_rn(f1.x, f1.z);   // {k4,k6}
        __half2 h2 = __floats2half2_rn(f0.y, f0.w);   // {k1,k3}
        __half2 h3 = __floats2half2_rn(f1.y, f1.w);   // {k5,k7}
        unsigned u0 = *reinterpret_cast<unsigned*>(&h0);
        unsigned u1 = *reinterpret_cast<unsigned*>(&h1);
        unsigned u2 = *reinterpret_cast<unsigned*>(&h2);
        unsigned u3 = *reinterpret_cast<unsigned*>(&h3);
        *(int4*)(xb + (size_t)idx * 8) = make_int4(u0, u1, u2, u3);
    } else {                                           // routing + work-list
        __shared__ int lcnt[NE], lbase[NE], lcur[NE];
        if (tid < NE) lcnt[tid] = 0;
        __syncthreads();
        for (int i = tid; i < NSLOT; i += 256)
            atomicAdd(&lcnt[eids[i]], 1);
        __syncthreads();
        if (tid == 0) {
            int acc = 0;
            for (int e = 0; e < NE; e++) { lbase[e] = acc; acc += lcnt[e]; }
        }
        __syncthreads();
        if (tid < NE) lcur[tid] = lbase[tid];
        __syncthreads();
        for (int i = tid; i < NSLOT; i += 256) {
            int e = eids[i];
            int pos = atomicAdd(&lcur[e], 1);
            tok[pos] = i >> 1;
            inv[i] = pos;
        }
        for (int t = tid; t < T_TOK; t += 256)
            tok[NSLOT + t] = t;
        if (tid < NE) { gcnt[tid] = lcnt[tid]; gbase[tid] = lbase[tid]; }
        if (tid == 0) {
            gcnt[NE] = T_TOK; gbase[NE] = NSLOT;
            int nt = 0;
            for (int e = 0; e < NE + 1; e++) {
                int c = (e < NE) ? lcnt[e] : T_TOK;
                for (int m = 0; m < c; m += 256) { tileE[nt] = e; tileM[nt] = m; nt++; }
            }
            *tileCnt = nt;                             // <= 32
            for (int i = nt; i < 64; i++) { tileE[i] = 0; tileM[i] = 0; }
        }
    }
}

// ---- GEMM 1: act[p,n] = silu(x@Wg)*(x@Wu). 256 rows x (64 gate + 64 up) per
// block, 512 threads = 8 waves (4x2 of 64x64 wave-tiles), BK=64, XOR-swizzle.
// Champion loop: {stage(A gld16 + B reg-dequant/ds_write); prefetch;
// sync; setprio+MFMA; sync}. LDS 48 KB single-buffer -> 2 blocks/CU.
__global__ __launch_bounds__(512) void k_gemm_gateup(
        const ushort* __restrict__ xb,
        const int* __restrict__ gup, const float* __restrict__ gus,
        const int* __restrict__ sup, const float* __restrict__ sus,
        const int* __restrict__ gcnt, const int* __restrict__ gbase,
        const int* __restrict__ tileCnt, const int* __restrict__ tileE,
        const int* __restrict__ tileM,
        const int* __restrict__ tokid, ushort* __restrict__ act) {
    int item = blockIdx.y;
    if (item >= *tileCnt) return;
    int tid = threadIdx.x;
    int e = tileE[item], m0 = tileM[item];
    int cnt = gcnt[e], base = gbase[e];
    int n0 = blockIdx.x * 64;                          // gate-col base (64 wide)
    const int* wp; const float* sc;
    if (e < NE) { wp = gup + (size_t)e * 256 * 2048; sc = gus + (size_t)e * 32 * 2048; }
    else        { wp = sup; sc = sus; }

    __shared__ __align__(16) ushort xs[256 * 64];      // 32 KB
    __shared__ __align__(16) ushort bs[128 * 64];      // 16 KB (48 KB total)

    int lane = tid & 63, wv = tid >> 6;                // 8 waves
    int lid = lane & 15, quad = lane >> 4;
    int wr = wv >> 1, wc = wv & 1;                     // 4x2 waves of 64x64
    int l8 = lane >> 3, l7 = lane & 7;
    int chunk = (l7 ^ l8) * 8;

    // A staging: 4 row-groups per lane (32 rows/wave), pre-swizzled source
    const ushort* aSrc[4];
    #pragma unroll
    for (int it = 0; it < 4; it++) {
        int rA = wv * 32 + it * 8 + l8;                // rA & 7 == l8
        int t = (m0 + rA < cnt) ? tokid[base + m0 + rA] : 0;
        aSrc[it] = xb + (size_t)t * K_DIM + chunk;
    }

    // B fused dequant: thread owns col nloc (of 128), k-words {kw0, kw0+1}
    int nloc = tid & 127;
    int kw0 = (tid >> 7) * 2;                          // {0,2,4,6}
    int bj = nloc & 63, bh = nloc >> 6;
    int ncol = (bj < 32) ? (n0 + bh * 32 + bj) : (I_DIM + n0 + bh * 32 + (bj - 32));
    int bd0 = nloc * 64 + ((kw0    ) ^ (nloc & 7)) * 8;
    int bd1 = nloc * 64 + ((kw0 + 1) ^ (nloc & 7)) * 8;

    const int NT = K_DIM / 64;                         // 32 k-tiles
    const int* wq = wp + (size_t)kw0 * 2048 + ncol;
    const float* sq = sc + ncol;
    unsigned w0 = (unsigned)wq[0];
    unsigned w1 = (unsigned)wq[2048];
    float s = *sq;
    wq += 16384; sq += 2048;

    f32x4 acc[4][4] = {};

    for (int t = 0; t < NT; ++t) {
        #pragma unroll
        for (int it = 0; it < 4; it++) {
            gld16(aSrc[it], &xs[(wv * 4 + it) * 512]);
            aSrc[it] += 64;
        }
        {
            __half2 S = __half2half2(__float2half(s));
            unsigned o[4];
            dq_word(w0, S, o); *(int4*)&bs[bd0] = make_int4(o[0], o[1], o[2], o[3]);
            dq_word(w1, S, o); *(int4*)&bs[bd1] = make_int4(o[0], o[1], o[2], o[3]);
        }
        if (t + 1 < NT) {                              // prefetch next k-step B
            w0 = (unsigned)wq[0];
            w1 = (unsigned)wq[2048];
            s = *sq;
            wq += 16384; sq += 2048;
        }
        __syncthreads();
        __builtin_amdgcn_s_setprio(1);
        #pragma unroll
        for (int ks = 0; ks < 2; ks++) {
            int slot = ((ks * 4 + quad) ^ l7) * 8;
            half8 a[4], b[4];
            #pragma unroll
            for (int mt = 0; mt < 4; mt++)
                a[mt] = *(const half8*)&xs[(wr * 64 + mt * 16 + lid) * 64 + slot];
            #pragma unroll
            for (int nt = 0; nt < 4; nt++)
                b[nt] = *(const half8*)&bs[(wc * 64 + nt * 16 + lid) * 64 + slot];
            #pragma unroll
            for (int mt = 0; mt < 4; mt++)
                #pragma unroll
                for (int nt = 0; nt < 4; nt++)
                    acc[mt][nt] = __builtin_amdgcn_mfma_f32_16x16x32_f16(
                        a[mt], b[nt], acc[mt][nt], 0, 0, 0);
        }
        __builtin_amdgcn_s_setprio(0);
        __syncthreads();
    }

    int c7 = lid & 7;
    int delta = ((c7 >> 1) + ((c7 & 1) << 2)) - c7;   // sigma^-1 on stored I index
    #pragma unroll
    for (int mt = 0; mt < 4; mt++) {
        #pragma unroll
        for (int i = 0; i < 4; i++) {
            int row = wr * 64 + mt * 16 + quad * 4 + i;
            if (m0 + row < cnt) {
                size_t p = (size_t)(base + m0 + row);
                #pragma unroll
                for (int nt = 0; nt < 2; nt++) {
                    float g = acc[mt][nt][i], u = acc[mt][nt + 2][i];
                    float vv = g / (1.f + __expf(-g)) * u;
                    int ncol2 = n0 + wc * 32 + nt * 16 + lid;
                    __half hb = __float2half(vv);
                    act[p * I_DIM + ncol2 + delta] = *reinterpret_cast<ushort*>(&hb);
                }
            }
        }
    }
}

// ---- GEMM 2: y[p,n] = (act @ Wd)[p,n]. 256 rows x 128 cols, 512 threads,
// same 8-wave / 48 KB / 2-blocks-per-CU loop as GEMM 1.
__global__ __launch_bounds__(512) void k_gemm_down(
        const ushort* __restrict__ actb,
        const int* __restrict__ dwp, const float* __restrict__ dsc,
        const int* __restrict__ sdp, const float* __restrict__ sds,
        const int* __restrict__ gcnt, const int* __restrict__ gbase,
        const int* __restrict__ tileCnt, const int* __restrict__ tileE,
        const int* __restrict__ tileM,
        ushort* __restrict__ y) {
    int item = blockIdx.y;
    if (item >= *tileCnt) return;
    int tid = threadIdx.x;
    int e = tileE[item], m0 = tileM[item];
    int cnt = gcnt[e], base = gbase[e];
    int n0 = blockIdx.x * 128;
    const int* wp; const float* sc;
    if (e < NE) { wp = dwp + (size_t)e * 128 * 2048; sc = dsc + (size_t)e * 16 * 2048; }
    else        { wp = sdp; sc = sds; }

    __shared__ __align__(16) ushort xs[256 * 64];      // 32 KB
    __shared__ __align__(16) ushort bs[128 * 64];      // 16 KB

    int lane = tid & 63, wv = tid >> 6;
    int lid = lane & 15, quad = lane >> 4;
    int wr = wv >> 1, wc = wv & 1;
    int l8 = lane >> 3, l7 = lane & 7;
    int chunk = (l7 ^ l8) * 8;

    const ushort* aSrc[4];
    #pragma unroll
    for (int it = 0; it < 4; it++) {
        int rA = wv * 32 + it * 8 + l8;
        int rr = m0 + rA; if (rr >= cnt) rr = cnt - 1;
        aSrc[it] = actb + (size_t)(base + rr) * I_DIM + chunk;
    }

    int nloc = tid & 127;
    int kw0 = (tid >> 7) * 2;
    int ncol = n0 + nloc;
    int bd0 = nloc * 64 + ((kw0    ) ^ (nloc & 7)) * 8;
    int bd1 = nloc * 64 + ((kw0 + 1) ^ (nloc & 7)) * 8;

    const int NT = I_DIM / 64;                         // 16 i-tiles
    const int* wq = wp + (size_t)kw0 * 2048 + ncol;
    const float* sq = sc + ncol;
    unsigned w0 = (unsigned)wq[0];
    unsigned w1 = (unsigned)wq[2048];
    float s = *sq;
    wq += 16384; sq += 2048;

    f32x4 acc[4][4] = {};

    for (int t = 0; t < NT; ++t) {
        #pragma unroll
        for (int it = 0; it < 4; it++) {
            gld16(aSrc[it], &xs[(wv * 4 + it) * 512]);
            aSrc[it] += 64;
        }
        {
            __half2 S = __half2half2(__float2half(s));
            unsigned o[4];
            dq_word(w0, S, o); *(int4*)&bs[bd0] = make_int4(o[0], o[1], o[2], o[3]);
            dq_word(w1, S, o); *(int4*)&bs[bd1] = make_int4(o[0], o[1], o[2], o[3]);
        }
        if (t + 1 < NT) {
            w0 = (unsigned)wq[0];
            w1 = (unsigned)wq[2048];
            s = *sq;
            wq += 16384; sq += 2048;
        }
        __syncthreads();
        __builtin_amdgcn_s_setprio(1);
        #pragma unroll
        for (int ks = 0; ks < 2; ks++) {
            int slot = ((ks * 4 + quad) ^ l7) * 8;
            half8 a[4], b[4];
            #pragma unroll
            for (int mt = 0; mt < 4; mt++)
                a[mt] = *(const half8*)&xs[(wr * 64 + mt * 16 + lid) * 64 + slot];
            #pragma unroll
            for (int nt = 0; nt < 4; nt++)
                b[nt] = *(const half8*)&bs[(wc * 64 + nt * 16 + lid) * 64 + slot];
            #pragma unroll
            for (int mt = 0; mt < 4; mt++)
                #pragma unroll
                for (int nt = 0; nt < 4; nt++)
                    acc[mt][nt] = __builtin_amdgcn_mfma_f32_16x16x32_f16(
                        a[mt], b[nt], acc[mt][nt], 0, 0, 0);
        }
        __builtin_amdgcn_s_setprio(0);
        __syncthreads();
    }

    #pragma unroll
    for (int mt = 0; mt < 4; mt++) {
        #pragma unroll
        for (int i = 0; i < 4; i++) {
            int row = wr * 64 + mt * 16 + quad * 4 + i;
            if (m0 + row < cnt) {
                ushort* yrow = y + (size_t)(base + m0 + row) * 2048 + n0 + wc * 64 + lid;
                #pragma unroll
                for (int nt = 0; nt < 4; nt++) {
                    __half hb = __float2half(acc[mt][nt][i]);
                    yrow[nt * 16] = *reinterpret_cast<ushort*>(&hb);
                }
            }
        }
    }
}

// out[t] = p0*y[inv[2t]] + p1*y[inv[2t+1]] + y[NSLOT+t]
__global__ __launch_bounds__(256) void k_combine(
        const ushort* __restrict__ y, const int* __restrict__ inv,
        const float* __restrict__ prb, float* __restrict__ out) {
    int idx = blockIdx.x * 256 + threadIdx.x;
    int t = idx >> 8;
    int c = (idx & 255) * 8;
    int p0 = inv[2 * t], p1 = inv[2 * t + 1];
    float w0 = prb[2 * t], w1 = prb[2 * t + 1];
    int4 a = *(const int4*)(y + (size_t)p0 * 2048 + c);
    int4 b = *(const int4*)(y + (size_t)p1 * 2048 + c);
    int4 s = *(const int4*)(y + (size_t)(NSLOT + t) * 2048 + c);
    const ushort* au = (const ushort*)&a;
    const ushort* bu = (const ushort*)&b;
    const ushort* su = (const ushort*)&s;
    float o[8];
    #pragma unroll
    for (int j = 0; j < 8; j++)
        o[j] = w0 * h2f(au[j]) + w1 * h2f(bu[j]) + h2f(su[j]);
    *(float4*)(out + (size_t)t * 2048 + c)     = *(float4*)&o[0];
    *(float4*)(out + (size_t)t * 2048 + c + 4) = *(float4*)&o[4];
}

extern "C" void kernel_launch(void* const* d_in, const int* in_sizes, int n_in,
                              void* d_out, int out_size, void* d_ws, size_t ws_size,
                              hipStream_t stream) {
    const float* x    = (const float*)d_in[0];
    const int*   gup  = (const int*)d_in[1];
    const float* gus  = (const float*)d_in[2];
    const int*   dwp  = (const int*)d_in[3];
    const float* dsc  = (const float*)d_in[4];
    const int*   sup  = (const int*)d_in[5];
    const float* sus  = (const float*)d_in[6];
    const int*   sdp  = (const int*)d_in[7];
    const float* sds  = (const float*)d_in[8];
    const int*   eids = (const int*)d_in[9];
    const float* prb  = (const float*)d_in[10];
    float* out = (float*)d_out;

    char*   ws      = (char*)d_ws;
    int*    gcnt    = (int*)(ws + 0);
    int*    gbase   = (int*)(ws + 64);
    int*    tileCnt = (int*)(ws + 128);
    int*    tileE   = (int*)(ws + 192);
    int*    tileM   = (int*)(ws + 448);
    int*    tok     = (int*)(ws + 1024);
    int*    inv     = (int*)(ws + 25600);
    ushort* xb      = (ushort*)(ws + WS_XB);
    ushort* act     = (ushort*)(ws + WS_ACT);
    ushort* y       = (ushort*)(ws + WS_Y);

    k_front<<<FRONT_GRID, 256, 0, stream>>>(
        x, xb, eids, gcnt, gbase, tileCnt, tileE, tileM, tok, inv);
    k_gemm_gateup<<<dim3(I_DIM / 64, MAXITEM), 512, 0, stream>>>(
        xb, gup, gus, sup, sus, gcnt, gbase, tileCnt, tileE, tileM, tok, act);
    k_gemm_down<<<dim3(K_DIM / 128, MAXITEM), 512, 0, stream>>>(
        act, dwp, dsc, sdp, sds, gcnt, gbase, tileCnt, tileE, tileM, y);
    k_combine<<<(T_TOK * K_DIM / 8) / 256, 256, 0, stream>>>(y, inv, prb, out);
}